// Round 1
// baseline (841.861 us; speedup 1.0000x reference)
//
#include <hip/hip_runtime.h>
#include <math.h>

#define BATCH 1024
#define TT    128
#define NB    13
#define HH    128
#define T_IN  64
#define NG    512   // 4*H gate rows

__device__ __forceinline__ float sigmoid_(float v) {
    // stable: exp(-inf)=0 -> 1 ; exp(+inf)=inf -> 0
    return 1.0f / (1.0f + __expf(-v));
}
__device__ __forceinline__ float tanh_(float v) {
    // stable at both ends: e=inf -> 1 ; e=0 -> -1
    float e = __expf(2.0f * v);
    return 1.0f - 2.0f / (e + 1.0f);
}

__global__ __launch_bounds__(512)
void lstm_temporal_kernel(const float* __restrict__ x,
                          const float* __restrict__ W_ih,
                          const float* __restrict__ W_hh,
                          const float* __restrict__ b_ih,
                          const float* __restrict__ b_hh,
                          const float* __restrict__ W_out,
                          const float* __restrict__ b_out,
                          float* __restrict__ out)
{
    const int b = blockIdx.x;   // one batch element per block
    const int j = threadIdx.x;  // gate row 0..511

    __shared__ float h_s[HH];
    __shared__ float x_s[NB];
    __shared__ float gate_s[NG];

    // ---- per-thread weights in registers ----
    float4 wh[32];  // W_hh row j (128 floats)
    {
        const float4* wrow = (const float4*)(W_hh + (size_t)j * HH);
#pragma unroll
        for (int k = 0; k < 32; ++k) wh[k] = wrow[k];
    }
    float wi[NB];   // W_ih row j (13 floats)
#pragma unroll
    for (int k = 0; k < NB; ++k) wi[k] = W_ih[j * NB + k];
    const float bias = b_ih[j] + b_hh[j];

    // y-compute role: 13 outputs x 8 partials = 104 threads
    const int m    = j >> 3;
    const int part = j & 7;
    float wo[16];
    float bo = 0.0f;
    if (j < 104) {
#pragma unroll
        for (int e = 0; e < 16; ++e) wo[e] = W_out[m * HH + part * 16 + e];
        if (part == 0) bo = b_out[m];
    }

    const float* xb = x   + (size_t)b * TT * NB;
    float*       ob = out + (size_t)b * TT * NB;

    // ---- init state ----
    float c = 0.0f;
    if (j < HH) h_s[j] = 0.0f;
    if (j < NB) {
        float x0 = xb[j];
        x_s[j] = x0;
        ob[j]  = x0;   // out[:,0,:] = x[:,0,:]
    }
    __syncthreads();

    // unified recurrence: step t input = (t<=64 ? x[:,t] : y_{t-1}); y_t -> out[:,t+1]
    for (int t = 0; t < TT - 1; ++t) {
        // ---- gates: row j = bias + W_ih[j,:]@x + W_hh[j,:]@h ----
        float acc = bias;
#pragma unroll
        for (int k = 0; k < NB; ++k) acc += wi[k] * x_s[k];
        const float4* h4 = (const float4*)h_s;
#pragma unroll
        for (int k = 0; k < 32; ++k) {
            float4 hv = h4[k];
            acc += wh[k].x * hv.x + wh[k].y * hv.y
                 + wh[k].z * hv.z + wh[k].w * hv.w;
        }
        gate_s[j] = acc;
        __syncthreads();  // S1: gates ready; all h_s/x_s readers done

        // ---- cell update (threads 0..127 own hidden units) ----
        if (j < HH) {
            float ig = sigmoid_(gate_s[j]);
            float fg = sigmoid_(gate_s[j + 128]);
            float gg = tanh_(gate_s[j + 256]);
            float og = sigmoid_(gate_s[j + 384]);
            c = fg * c + ig * gg;
            h_s[j] = og * tanh_(c);
        }
        // teacher-phase prefetch of next input (disjoint from auto-phase writers)
        if (t + 1 <= T_IN && j < NB) {
            x_s[j] = xb[(t + 1) * NB + j];
        }
        __syncthreads();  // S2: h_s ready

        // ---- projection y = W_out @ h + b_out ----
        float s = 0.0f;
        if (j < 104) {
            const float4* hh = (const float4*)(h_s + part * 16);
#pragma unroll
            for (int e = 0; e < 4; ++e) {
                float4 hv = hh[e];
                s += wo[e * 4 + 0] * hv.x + wo[e * 4 + 1] * hv.y
                   + wo[e * 4 + 2] * hv.z + wo[e * 4 + 3] * hv.w;
            }
        }
        if (j < 128) {  // full waves 0-1 participate: all shfl sources defined
            s += __shfl_down(s, 4, 64);
            s += __shfl_down(s, 2, 64);
            s += __shfl_down(s, 1, 64);
            if (part == 0 && j < 104) {
                float y = s + bo;
                ob[(t + 1) * NB + m] = y;
                // y_t feeds step t+1 when t+1 > T_IN (i.e. t >= 64); last step feeds nothing
                if (t >= T_IN && t < TT - 2) x_s[m] = y;
            }
        }
        __syncthreads();  // S3: x_s update visible; y-phase h_s reads done
    }
}

extern "C" void kernel_launch(void* const* d_in, const int* in_sizes, int n_in,
                              void* d_out, int out_size, void* d_ws, size_t ws_size,
                              hipStream_t stream)
{
    const float* x     = (const float*)d_in[0];
    const float* W_ih  = (const float*)d_in[1];
    const float* W_hh  = (const float*)d_in[2];
    const float* b_ih  = (const float*)d_in[3];
    const float* b_hh  = (const float*)d_in[4];
    const float* W_out = (const float*)d_in[5];
    const float* b_out = (const float*)d_in[6];
    float* out = (float*)d_out;

    lstm_temporal_kernel<<<BATCH, 512, 0, stream>>>(
        x, W_ih, W_hh, b_ih, b_hh, W_out, b_out, out);
}

// Round 2
// 379.157 us; speedup vs baseline: 2.2204x; 2.2204x over previous
//
#include <hip/hip_runtime.h>
#include <math.h>

#define BATCH 1024
#define TT    128
#define NBI   13
#define HH    128
#define T_INP 64
#define NG    512

typedef _Float16 half2v __attribute__((ext_vector_type(2)));

#if __has_builtin(__builtin_amdgcn_fdot2)
#define HAS_FDOT2 1
#else
#define HAS_FDOT2 0
#endif

__device__ __forceinline__ float dot2acc(float w, float h, float acc) {
#if HAS_FDOT2
    return __builtin_amdgcn_fdot2(__builtin_bit_cast(half2v, w),
                                  __builtin_bit_cast(half2v, h), acc, false);
#else
    half2v a = __builtin_bit_cast(half2v, w);
    half2v b = __builtin_bit_cast(half2v, h);
    return acc + (float)a[0] * (float)b[0] + (float)a[1] * (float)b[1];
#endif
}

__device__ __forceinline__ unsigned short f16b(float v) {
    return __builtin_bit_cast(unsigned short, (_Float16)v);
}
__device__ __forceinline__ float sigmoid_(float v) {
    return 1.0f / (1.0f + __expf(-v));
}
__device__ __forceinline__ float tanh_(float v) {
    float e = __expf(2.0f * v);
    return 1.0f - 2.0f / (e + 1.0f);
}

// ---- ws layout (bytes) ----
#define WS_WHH   0            // ushort[512*128] teacher W_hh (f16)
#define WS_WHAT  131072       // ushort[512*128] folded Ŵ = W_hh + W_ih@W_out (f16)
#define WS_WIH   262144       // ushort[512*16]  W_ih padded 13->16 (f16)
#define WS_WOUT  278528       // ushort[13*128]  W_out (f16)
#define WS_BT    282624       // float[512] teacher bias = b_ih+b_hh
#define WS_BA    284672       // float[512] auto bias = b_ih+b_hh + W_ih@b_out

__global__ void fold_kernel(const float* __restrict__ W_ih,
                            const float* __restrict__ W_hh,
                            const float* __restrict__ b_ih,
                            const float* __restrict__ b_hh,
                            const float* __restrict__ W_out,
                            const float* __restrict__ b_out,
                            unsigned char* __restrict__ ws)
{
    const int j = blockIdx.x;   // gate row 0..511
    const int k = threadIdx.x;  // hidden col 0..127
    unsigned short* whh16  = (unsigned short*)(ws + WS_WHH);
    unsigned short* what16 = (unsigned short*)(ws + WS_WHAT);
    unsigned short* wih16  = (unsigned short*)(ws + WS_WIH);
    unsigned short* wout16 = (unsigned short*)(ws + WS_WOUT);
    float* bias_t = (float*)(ws + WS_BT);
    float* bias_a = (float*)(ws + WS_BA);

    float whh = W_hh[j * HH + k];
    float acc = whh;
#pragma unroll
    for (int m = 0; m < NBI; ++m)
        acc += W_ih[j * NBI + m] * W_out[m * HH + k];
    whh16[j * HH + k]  = f16b(whh);
    what16[j * HH + k] = f16b(acc);

    if (k < 16) wih16[j * 16 + k] = (k < NBI) ? f16b(W_ih[j * NBI + k]) : 0;
    if (k == 0) {
        float bt = b_ih[j] + b_hh[j];
        bias_t[j] = bt;
        float ba = bt;
#pragma unroll
        for (int m = 0; m < NBI; ++m) ba += W_ih[j * NBI + m] * b_out[m];
        bias_a[j] = ba;
    }
    if (j < NBI) wout16[j * HH + k] = f16b(W_out[j * HH + k]);
}

__global__ __launch_bounds__(512, 4)
void lstm_main(const float* __restrict__ x,
               const float* __restrict__ b_out,
               const unsigned char* __restrict__ ws,
               float* __restrict__ out)
{
    const int b = blockIdx.x;
    const int j = threadIdx.x;

    const unsigned short* whh16  = (const unsigned short*)(ws + WS_WHH);
    const unsigned short* what16 = (const unsigned short*)(ws + WS_WHAT);
    const unsigned short* wih16  = (const unsigned short*)(ws + WS_WIH);
    const unsigned short* wout16 = (const unsigned short*)(ws + WS_WOUT);
    const float* bias_t = (const float*)(ws + WS_BT);
    const float* bias_a = (const float*)(ws + WS_BA);

    __shared__ __align__(16) unsigned short h_s[HH];  // f16 hidden state
    __shared__ __align__(16) unsigned short x_s[16];  // f16 input (padded)
    __shared__ float gate_s[NG];

    // ---- register-resident weights: 64 VGPRs of f16-packed W row ----
    float4 whf[16];
    {
        const float4* wp = (const float4*)(whh16 + j * HH);
#pragma unroll
        for (int c2 = 0; c2 < 16; ++c2) whf[c2] = wp[c2];
    }
    float4 wif0, wif1;
    {
        const float4* ip = (const float4*)(wih16 + j * 16);
        wif0 = ip[0]; wif1 = ip[1];
    }
    float bias_cur = bias_t[j];
    const float bias_auto = bias_a[j];

    // projection role: 13 outputs x 8 partials = 104 threads
    const int m = j >> 3, part = j & 7;
    float4 wof0 = {0,0,0,0}, wof1 = {0,0,0,0};
    float bo = 0.0f;
    if (j < 104) {
        const float4* op = (const float4*)(wout16 + m * HH + part * 16);
        wof0 = op[0]; wof1 = op[1];
        if (part == 0) bo = b_out[m];
    }

    const float* xb = x   + (size_t)b * TT * NBI;
    float*       ob = out + (size_t)b * TT * NBI;

    float c = 0.0f;
    if (j < HH) h_s[j] = 0;
    if (j < 16) {
        float v = (j < NBI) ? xb[j] : 0.0f;
        x_s[j] = f16b(v);
        if (j < NBI) ob[j] = v;   // out[:,0,:] = x[:,0,:]
    }
    __syncthreads();

    for (int t = 0; t < TT - 1; ++t) {
        if (t == T_INP + 1) {
            // switch to folded weights Ŵ, b̂ (auto phase: x never materialized)
            const float4* ap = (const float4*)(what16 + j * HH);
#pragma unroll
            for (int c2 = 0; c2 < 16; ++c2) whf[c2] = ap[c2];
            bias_cur = bias_auto;
        }

        // ---- G phase: gate row j = bias + W·h (+ W_ih·x in teacher phase) ----
        float a0 = bias_cur, a1 = 0.f, a2 = 0.f, a3 = 0.f;
        const float4* h4 = (const float4*)h_s;
#pragma unroll
        for (int cb = 0; cb < 16; ++cb) {
            float4 hv = h4[cb];
            float4 wv = whf[cb];
            a0 = dot2acc(wv.x, hv.x, a0);
            a1 = dot2acc(wv.y, hv.y, a1);
            a2 = dot2acc(wv.z, hv.z, a2);
            a3 = dot2acc(wv.w, hv.w, a3);
        }
        float acc = (a0 + a1) + (a2 + a3);
        if (t <= T_INP) {
            const float4* x4 = (const float4*)x_s;
            float4 xv0 = x4[0], xv1 = x4[1];
            acc = dot2acc(wif0.x, xv0.x, acc);
            acc = dot2acc(wif0.y, xv0.y, acc);
            acc = dot2acc(wif0.z, xv0.z, acc);
            acc = dot2acc(wif0.w, xv0.w, acc);
            acc = dot2acc(wif1.x, xv1.x, acc);
            acc = dot2acc(wif1.y, xv1.y, acc);
            acc = dot2acc(wif1.z, xv1.z, acc);
            acc = dot2acc(wif1.w, xv1.w, acc);
        }
        gate_s[j] = acc;

        // ---- lagged projection: out[t] = W_out h^(t) + b_out (t>=1) ----
        float ps = 0.0f;
        if (t >= 1 && j < 104) {
            const float4* hp = ((const float4*)h_s) + part * 2;
            float4 p0 = hp[0], p1 = hp[1];
            ps = dot2acc(wof0.x, p0.x, ps);
            ps = dot2acc(wof0.y, p0.y, ps);
            ps = dot2acc(wof0.z, p0.z, ps);
            ps = dot2acc(wof0.w, p0.w, ps);
            ps = dot2acc(wof1.x, p1.x, ps);
            ps = dot2acc(wof1.y, p1.y, ps);
            ps = dot2acc(wof1.z, p1.z, ps);
            ps = dot2acc(wof1.w, p1.w, ps);
        }
        if (j < 128) {
            ps += __shfl_down(ps, 4, 64);
            ps += __shfl_down(ps, 2, 64);
            ps += __shfl_down(ps, 1, 64);
            if (t >= 1 && part == 0 && j < 104)
                ob[t * NBI + m] = ps + bo;
        }
        __syncthreads();  // gates ready; h_s/x_s readers done

        // ---- U phase: cell update ----
        if (j < HH) {
            float ig = sigmoid_(gate_s[j]);
            float fg = sigmoid_(gate_s[j + 128]);
            float gg = tanh_(gate_s[j + 256]);
            float og = sigmoid_(gate_s[j + 384]);
            c = fg * c + ig * gg;
            h_s[j] = f16b(og * tanh_(c));
        } else if (j < 144) {
            if (t + 1 <= T_INP) {
                int k = j - 128;
                float v = (k < NBI) ? xb[(t + 1) * NBI + k] : 0.0f;
                x_s[k] = f16b(v);
            }
        }
        __syncthreads();  // h_s (and x_s) ready for next G
    }

    // ---- epilogue: out[127] = W_out h^(127) + b_out ----
    {
        float ps = 0.0f;
        if (j < 104) {
            const float4* hp = ((const float4*)h_s) + part * 2;
            float4 p0 = hp[0], p1 = hp[1];
            ps = dot2acc(wof0.x, p0.x, ps);
            ps = dot2acc(wof0.y, p0.y, ps);
            ps = dot2acc(wof0.z, p0.z, ps);
            ps = dot2acc(wof0.w, p0.w, ps);
            ps = dot2acc(wof1.x, p1.x, ps);
            ps = dot2acc(wof1.y, p1.y, ps);
            ps = dot2acc(wof1.z, p1.z, ps);
            ps = dot2acc(wof1.w, p1.w, ps);
        }
        if (j < 128) {
            ps += __shfl_down(ps, 4, 64);
            ps += __shfl_down(ps, 2, 64);
            ps += __shfl_down(ps, 1, 64);
            if (part == 0 && j < 104)
                ob[(TT - 1) * NBI + m] = ps + bo;
        }
    }
}

extern "C" void kernel_launch(void* const* d_in, const int* in_sizes, int n_in,
                              void* d_out, int out_size, void* d_ws, size_t ws_size,
                              hipStream_t stream)
{
    const float* x     = (const float*)d_in[0];
    const float* W_ih  = (const float*)d_in[1];
    const float* W_hh  = (const float*)d_in[2];
    const float* b_ih  = (const float*)d_in[3];
    const float* b_hh  = (const float*)d_in[4];
    const float* W_out = (const float*)d_in[5];
    const float* b_out = (const float*)d_in[6];
    float* out = (float*)d_out;
    unsigned char* ws = (unsigned char*)d_ws;

    fold_kernel<<<NG, HH, 0, stream>>>(W_ih, W_hh, b_ih, b_hh, W_out, b_out, ws);
    lstm_main<<<BATCH, 512, 0, stream>>>(x, b_out, ws, out);
}